// Round 3
// baseline (142.971 us; speedup 1.0000x reference)
//
#include <hip/hip_runtime.h>
#include <hip/hip_bf16.h>
#include <math.h>
#include <stdint.h>

#define EPS 1e-5f

typedef __attribute__((ext_vector_type(8))) short bf16x8;
typedef __attribute__((ext_vector_type(16))) float f32x16;

__device__ __forceinline__ ushort f2bf(float f) {
    union { float f; unsigned u; } v; v.f = f;
    unsigned r = (v.u + 0x7FFFu + ((v.u >> 16) & 1u)) >> 16;
    return (ushort)r;
}

__device__ __forceinline__ void dma16(const void* g, void* l) {
    __builtin_amdgcn_global_load_lds(
        (__attribute__((address_space(1))) const void*)(uintptr_t)g,
        (__attribute__((address_space(3))) void*)(uintptr_t)l,
        16, 0, 0);
}

// ---------------------------------------------------------------------------
// Kernel 1: transpose x -> xT[b][y 66][c 66][ic 128] bf16 (borders zero),
// plus pooling partials [b][y][ic].  grid = 32*64 blocks (b, y), 256 thr.
// ---------------------------------------------------------------------------
__global__ __launch_bounds__(256) void transpose_kernel(const float* __restrict__ x,
                                                        ushort* __restrict__ xT,
                                                        float* __restrict__ partial) {
    __shared__ float T[128][65];
    int b = blockIdx.x >> 6;
    int y = blockIdx.x & 63;
    int t = threadIdx.x;

    // phase 1: load x[b][ic][y][:], sum, stash in LDS
    int ic2 = t >> 1, half = t & 1;
    const float4* src = (const float4*)(x + (((size_t)b * 128 + ic2) * 64 + y) * 64 + half * 32);
    float s = 0.f;
#pragma unroll
    for (int i = 0; i < 8; ++i) {
        float4 v = src[i];
        int c0 = half * 32 + i * 4;
        T[ic2][c0] = v.x; T[ic2][c0 + 1] = v.y; T[ic2][c0 + 2] = v.z; T[ic2][c0 + 3] = v.w;
        s += v.x + v.y + v.z + v.w;
    }
    s += __shfl_xor(s, 1, 64);
    if (half == 0) partial[((size_t)b * 64 + y) * 128 + ic2] = s;
    __syncthreads();

    // phase 2: write xT[b][y+1][col+1][ic] bf16
    int col = t >> 2, icq = t & 3;
    uint pk[16];
#pragma unroll
    for (int j = 0; j < 16; ++j) {
        float f0 = T[icq * 32 + 2 * j][col];
        float f1 = T[icq * 32 + 2 * j + 1][col];
        pk[j] = (uint)f2bf(f0) | ((uint)f2bf(f1) << 16);
    }
    ushort* dst = xT + ((((size_t)b * 66 + y + 1) * 66) + col + 1) * 128 + icq * 32;
    ((uint4*)dst)[0] = make_uint4(pk[0], pk[1], pk[2], pk[3]);
    ((uint4*)dst)[1] = make_uint4(pk[4], pk[5], pk[6], pk[7]);
    ((uint4*)dst)[2] = make_uint4(pk[8], pk[9], pk[10], pk[11]);
    ((uint4*)dst)[3] = make_uint4(pk[12], pk[13], pk[14], pk[15]);

    // borders: full pad rows 0 and 65
    uint4 z = make_uint4(0, 0, 0, 0);
    if (y == 0) {
        uint4* row0 = (uint4*)(xT + ((size_t)b * 66 + 0) * 66 * 128);
        for (int i = t; i < 1056; i += 256) row0[i] = z;
    }
    if (y == 63) {
        uint4* row65 = (uint4*)(xT + ((size_t)b * 66 + 65) * 66 * 128);
        for (int i = t; i < 1056; i += 256) row65[i] = z;
    }
    // pad cols 0 and 65 of this row
    if (t < 32) {
        int c = (t >> 4) * 65;
        int i = t & 15;
        *(uint4*)(xT + ((((size_t)b * 66 + y + 1) * 66) + c) * 128 + i * 8) = z;
    }
}

// ---------------------------------------------------------------------------
// Kernel 2: reduce partials -> pooled[b][ic]
// ---------------------------------------------------------------------------
__global__ __launch_bounds__(256) void reduce_kernel(const float* __restrict__ partial,
                                                     float* __restrict__ pooled) {
    int idx = blockIdx.x * 256 + threadIdx.x;   // 4096
    int b = idx >> 7, ic = idx & 127;
    const float* p = partial + (size_t)b * 64 * 128 + ic;
    float s = 0.f;
#pragma unroll 8
    for (int y = 0; y < 64; ++y) s += p[y * 128];
    pooled[idx] = s * (1.0f / 4096.0f);
}

// ---------------------------------------------------------------------------
// Kernel 3: SE MLP -> att[32,4].
// ---------------------------------------------------------------------------
__global__ void se_kernel(const float* __restrict__ pooled,
                          const float* __restrict__ se_w1,
                          const float* __restrict__ gn1_s, const float* __restrict__ gn1_b,
                          const float* __restrict__ se_w2,
                          const float* __restrict__ gn2_s, const float* __restrict__ gn2_b,
                          float* __restrict__ att) {
    int b = threadIdx.x;
    if (b >= 32) return;
    const float* p = pooled + b * 128;

    float h1[8];
#pragma unroll
    for (int j = 0; j < 8; ++j) {
        float s = 0.f;
        for (int c = 0; c < 128; ++c) s += p[c] * se_w1[j * 128 + c];
        h1[j] = s;
    }
    float m = 0.f;
#pragma unroll
    for (int j = 0; j < 8; ++j) m += h1[j];
    m *= 0.125f;
    float var = 0.f;
#pragma unroll
    for (int j = 0; j < 8; ++j) { float d = h1[j] - m; var += d * d; }
    var *= 0.125f;
    float inv = rsqrtf(var + EPS);
#pragma unroll
    for (int j = 0; j < 8; ++j) {
        float t = (h1[j] - m) * inv * gn1_s[j] + gn1_b[j];
        float sp = (t > 20.f) ? t : log1pf(expf(t));
        h1[j] = t * tanhf(sp);
    }
    float h2[4];
#pragma unroll
    for (int k = 0; k < 4; ++k) {
        float s = 0.f;
#pragma unroll
        for (int j = 0; j < 8; ++j) s += h1[j] * se_w2[k * 8 + j];
        h2[k] = s;
    }
    float m2 = 0.25f * (h2[0] + h2[1] + h2[2] + h2[3]);
    float v2 = 0.f;
#pragma unroll
    for (int k = 0; k < 4; ++k) { float d = h2[k] - m2; v2 += d * d; }
    v2 *= 0.25f;
    float inv2 = rsqrtf(v2 + EPS);
#pragma unroll
    for (int k = 0; k < 4; ++k) {
        float t = (h2[k] - m2) * inv2 * gn2_s[k] + gn2_b[k];
        att[b * 4 + k] = 1.0f / (1.0f + expf(-t));
    }
}

// ---------------------------------------------------------------------------
// Kernel 4: bc[b][oc] = att @ bias
// ---------------------------------------------------------------------------
__global__ __launch_bounds__(256) void bc_kernel(const float* __restrict__ att,
                                                 const float* __restrict__ bias,
                                                 float* __restrict__ bc) {
    int idx = blockIdx.x * 256 + threadIdx.x;   // 4096
    int b = idx >> 7, oc = idx & 127;
    bc[idx] = att[b * 4 + 0] * bias[oc] + att[b * 4 + 1] * bias[128 + oc]
            + att[b * 4 + 2] * bias[256 + oc] + att[b * 4 + 3] * bias[384 + oc];
}

// ---------------------------------------------------------------------------
// Kernel 5: aggregate weights -> bf16, 32x32x16 A-fragment-major.
// cid = ((h*9+s)*4 + icb)*4 + M32 ; lane l: oc = M32*32+(l&31),
// ic = h*64 + icb*16 + (l>>5)*8 + j (j=0..7).  aggw[((b*288+cid)*64+l)*8+j]
// ---------------------------------------------------------------------------
__global__ __launch_bounds__(256) void aggw_kernel(const float* __restrict__ weight,
                                                   const float* __restrict__ att,
                                                   ushort* __restrict__ aggw) {
    int t = blockIdx.x * 256 + threadIdx.x;     // 72*256 = 18432 = 288*64
    int l = t & 63;
    int cid = t >> 6;                            // 0..287
    int M32 = cid & 3;
    int rest = cid >> 2;                         // (h*9+s)*4 + icb
    int icb = rest & 3;
    int hs = rest >> 2;                          // 0..17
    int s = hs % 9;
    int h = hs / 9;
    int oc = M32 * 32 + (l & 31);
    int ic0 = h * 64 + icb * 16 + (l >> 5) * 8;

    float wv[4][8];
#pragma unroll
    for (int k = 0; k < 4; ++k)
#pragma unroll
        for (int j = 0; j < 8; ++j)
            wv[k][j] = weight[(((size_t)(k * 128 + oc)) * 128 + ic0 + j) * 9 + s];

    for (int b = 0; b < 32; ++b) {
        float a0 = att[b * 4 + 0], a1 = att[b * 4 + 1], a2 = att[b * 4 + 2], a3 = att[b * 4 + 3];
        uint pk[4];
#pragma unroll
        for (int p = 0; p < 4; ++p) {
            float f0 = a0 * wv[0][2 * p] + a1 * wv[1][2 * p] + a2 * wv[2][2 * p] + a3 * wv[3][2 * p];
            float f1 = a0 * wv[0][2 * p + 1] + a1 * wv[1][2 * p + 1] + a2 * wv[2][2 * p + 1] + a3 * wv[3][2 * p + 1];
            pk[p] = (uint)f2bf(f0) | ((uint)f2bf(f1) << 16);
        }
        *(uint4*)(aggw + ((size_t)(b * 288 + cid) * 64 + l) * 8) = make_uint4(pk[0], pk[1], pk[2], pk[3]);
    }
}

// ---------------------------------------------------------------------------
// Kernel 6: implicit-GEMM conv, mfma_f32_32x32x16_bf16.
// grid 1024 = 32 b * 32 tiles(2 rows); 256 thr = 4 waves (wm: oc-64, wn: row).
// LDS [4 rows][66 c][64 ic-half], DMA-staged with source-side XOR swizzle.
// ---------------------------------------------------------------------------
__global__ __launch_bounds__(256, 4) void conv_kernel(const ushort* __restrict__ xT,
                                                      const ushort* __restrict__ aggw,
                                                      const float* __restrict__ bc,
                                                      float* __restrict__ out) {
    __shared__ ushort lds[4 * 66 * 64];          // 33792 B

    int bid = blockIdx.x;
    int wg = (bid & 7) * 128 + (bid >> 3);       // XCD-bijective swizzle (1024%8==0)
    int b = wg >> 5;
    int y0 = (wg & 31) * 2;

    int tid = threadIdx.x;
    int l = tid & 63, w = tid >> 6;
    int wm = w >> 1, wn = w & 1;
    int l31 = l & 31, lhi = l >> 5;

    const ushort* xTb = xT + ((size_t)b * 66 + y0) * 66 * 128;
    const ushort* Ab = aggw + (size_t)b * 147456 + (size_t)l * 8;

    f32x16 acc[2][2];
#pragma unroll
    for (int m = 0; m < 2; ++m)
#pragma unroll
        for (int n = 0; n < 2; ++n)
#pragma unroll
            for (int q = 0; q < 16; ++q) acc[m][n][q] = 0.f;

    int tq = tid >> 3;       // 0..31: rc step within issue
    int uc = tid & 7;        // 16B ic-chunk slot (constant per thread)

#pragma unroll 1
    for (int h = 0; h < 2; ++h) {
        if (h) __syncthreads();
        // ---- DMA stage: 2112 chunks of 16B, source-side XOR swizzle ----
        {
            int c = tq;      // c = rc % 66, maintained incrementally
#pragma unroll
            for (int i = 0; i < 8; ++i) {
                int rc = i * 32 + tq;
                const ushort* src = xTb + (size_t)rc * 128 + h * 64 + ((uc ^ (c & 7)) << 3);
                dma16(src, &lds[rc * 64 + uc * 8]);
                c += 32; if (c >= 66) c -= 66;
            }
            if (w == 0) {    // tail: chunks 2048..2111 (rc 256..263)
                int rc = 256 + (tid >> 3);
                int c2 = rc - 198;               // rc % 66
                const ushort* src = xTb + (size_t)rc * 128 + h * 64 + ((uc ^ (c2 & 7)) << 3);
                dma16(src, &lds[rc * 64 + uc * 8]);
            }
        }
        __syncthreads();

        // ---- 36 K-steps (9 taps x 4 ic-blocks of 16) ----
#pragma unroll
        for (int s = 0; s < 9; ++s) {
            const int kh = s / 3, kw = s % 3;
            int rbase = (wn + kh) * 66;
            int c0 = l31 + kw;
            int c1 = 32 + l31 + kw;
            int o0 = (rbase + c0) * 64, s0 = c0 & 7;
            int o1 = (rbase + c1) * 64, s1 = c1 & 7;
#pragma unroll
            for (int icb = 0; icb < 4; ++icb) {
                int cid = ((h * 9 + s) * 4 + icb) * 4 + wm * 2;
                bf16x8 a0 = *(const bf16x8*)(Ab + (size_t)cid * 512);
                bf16x8 a1 = *(const bf16x8*)(Ab + (size_t)cid * 512 + 512);
                int ucl = icb * 2 + lhi;
                bf16x8 b0 = *(const bf16x8*)&lds[o0 + ((ucl ^ s0) << 3)];
                bf16x8 b1 = *(const bf16x8*)&lds[o1 + ((ucl ^ s1) << 3)];
                acc[0][0] = __builtin_amdgcn_mfma_f32_32x32x16_bf16(a0, b0, acc[0][0], 0, 0, 0);
                acc[0][1] = __builtin_amdgcn_mfma_f32_32x32x16_bf16(a0, b1, acc[0][1], 0, 0, 0);
                acc[1][0] = __builtin_amdgcn_mfma_f32_32x32x16_bf16(a1, b0, acc[1][0], 0, 0, 0);
                acc[1][1] = __builtin_amdgcn_mfma_f32_32x32x16_bf16(a1, b1, acc[1][1], 0, 0, 0);
            }
        }
    }

    // ---- epilogue: + bc, store ----
    int y = y0 + wn;
    const float* bcb = bc + b * 128;
#pragma unroll
    for (int m = 0; m < 2; ++m)
#pragma unroll
        for (int nb = 0; nb < 2; ++nb)
#pragma unroll
            for (int q = 0; q < 16; ++q) {
                int oc = wm * 64 + m * 32 + (q & 3) + 8 * (q >> 2) + 4 * lhi;
                out[(((size_t)b * 128 + oc) * 64 + y) * 64 + nb * 32 + l31] = acc[m][nb][q] + bcb[oc];
            }
}

// ---------------------------------------------------------------------------
extern "C" void kernel_launch(void* const* d_in, const int* in_sizes, int n_in,
                              void* d_out, int out_size, void* d_ws, size_t ws_size,
                              hipStream_t stream) {
    const float* x      = (const float*)d_in[0];
    const float* weight = (const float*)d_in[1];
    const float* bias   = (const float*)d_in[2];
    const float* se_w1  = (const float*)d_in[3];
    const float* gn1_s  = (const float*)d_in[4];
    const float* gn1_b  = (const float*)d_in[5];
    const float* se_w2  = (const float*)d_in[6];
    const float* gn2_s  = (const float*)d_in[7];
    const float* gn2_b  = (const float*)d_in[8];
    float* out = (float*)d_out;

    // workspace layout
    float*  pooled  = (float*)d_ws;                             // 16 KB
    float*  att     = (float*)((char*)d_ws + 16384);            // 512 B
    float*  bcbuf   = (float*)((char*)d_ws + 20480);            // 16 KB
    float*  partial = (float*)((char*)d_ws + 65536);            // 1 MB (overlaps aggw, consumed first)
    ushort* aggw    = (ushort*)((char*)d_ws + 65536);           // 9.44 MB
    ushort* xT      = (ushort*)((char*)d_ws + 10485760);        // 35.7 MB  (total ~46.2 MB)

    transpose_kernel<<<32 * 64, 256, 0, stream>>>(x, xT, partial);
    reduce_kernel<<<16, 256, 0, stream>>>(partial, pooled);
    se_kernel<<<1, 64, 0, stream>>>(pooled, se_w1, gn1_s, gn1_b, se_w2, gn2_s, gn2_b, att);
    bc_kernel<<<16, 256, 0, stream>>>(att, bias, bcbuf);
    aggw_kernel<<<72, 256, 0, stream>>>(weight, att, aggw);
    conv_kernel<<<1024, 256, 0, stream>>>(xT, aggw, bcbuf, out);
}